// Round 1
// baseline (1333.025 us; speedup 1.0000x reference)
//
#include <hip/hip_runtime.h>

// out[b,s,t] = sum_d in[b,t,s,d] * aff[d,t]
// B=8, T=128, S=256, D=1024, fp32. Memory-bound: 1.074 GB input read once.
constexpr int B = 8, T = 128, S = 256, D = 1024;

// One block per (b*T+t, s_half). Block = 256 threads = 4 waves.
// Lanes span d (contiguous float4 loads); each wave handles one s-row per
// iteration, 32 rows total. Affine column aff[:,t] preloaded into registers.
__global__ __launch_bounds__(256) void filtersum_kernel(
    const float* __restrict__ in, const float* __restrict__ aff,
    float* __restrict__ out) {
  const int bt   = blockIdx.x;        // b*T + t
  const int b    = bt >> 7;           // / T (T=128)
  const int t    = bt & (T - 1);      // % T
  const int half = blockIdx.y;        // s-half: 0 or 1
  const int wave = threadIdx.x >> 6;  // 0..3
  const int lane = threadIdx.x & 63;

  // Preload affine column t: lane needs d = k*256 + lane*4 + j, k=0..3, j=0..3.
  // Strided (stride T floats) scalar loads; affine is 512 KB -> L2/L3 resident.
  float4 a[4];
#pragma unroll
  for (int k = 0; k < 4; ++k) {
    const int d = k * 256 + lane * 4;
    a[k].x = aff[(size_t)(d + 0) * T + t];
    a[k].y = aff[(size_t)(d + 1) * T + t];
    a[k].z = aff[(size_t)(d + 2) * T + t];
    a[k].w = aff[(size_t)(d + 3) * T + t];
  }

  const size_t in_base = (size_t)bt * S * D;  // in[b,t,0,0]
  const int s_begin = half * (S / 2) + wave;
  const int s_end   = half * (S / 2) + (S / 2);

  for (int s = s_begin; s < s_end; s += 4) {
    const float* row = in + in_base + (size_t)s * D;
    float partial = 0.f;
#pragma unroll
    for (int k = 0; k < 4; ++k) {
      const float4 v =
          *reinterpret_cast<const float4*>(row + k * 256 + lane * 4);
      partial += v.x * a[k].x + v.y * a[k].y + v.z * a[k].z + v.w * a[k].w;
    }
    // 64-lane wave reduction
#pragma unroll
    for (int off = 32; off > 0; off >>= 1)
      partial += __shfl_down(partial, off, 64);
    if (lane == 0) out[((size_t)b * S + s) * T + t] = partial;
  }
}

extern "C" void kernel_launch(void* const* d_in, const int* in_sizes, int n_in,
                              void* d_out, int out_size, void* d_ws,
                              size_t ws_size, hipStream_t stream) {
  const float* in  = (const float*)d_in[0];
  const float* aff = (const float*)d_in[1];
  float* out = (float*)d_out;
  dim3 grid(B * T, 2);
  filtersum_kernel<<<grid, 256, 0, stream>>>(in, aff, out);
}